// Round 1
// baseline (17696.057 us; speedup 1.0000x reference)
//
#include <hip/hip_runtime.h>
#include <hip/hip_cooperative_groups.h>
#include <cstddef>

namespace cg = cooperative_groups;

static constexpr int   NN      = 2048;
static constexpr int   TPB     = 256;
static constexpr int   MAX_IT  = 100;
static constexpr float EPS     = 0.1f;
static constexpr float INV_EPS = 10.0f;
// logf(1/2048 + 1e-8)
static constexpr float LOG_AB  = -7.6245985063594f;
static constexpr float THRESH  = 0.1f;

// ---------------------------------------------------------------------------
// Cost matrix build: C[i][j] = sum_d (x[i,d]-y[j,d])^2, optional CT = C^T.
// 64x64 output tile per block, LDS-staged x/y tiles, 4x4 register tile/thread.
// ---------------------------------------------------------------------------
__global__ __launch_bounds__(TPB)
void build_cost(const float* __restrict__ x, const float* __restrict__ y,
                float* __restrict__ C, float* __restrict__ CT,
                int c_aligned, int use_ct)
{
    __shared__ float xs[64][65];   // +1 pad: conflict-free column reads
    __shared__ float ys[64][65];
    const int t  = threadIdx.x;
    const int bi = blockIdx.y, bj = blockIdx.x;

#pragma unroll
    for (int k = 0; k < 16; ++k) {
        int idx = t + TPB * k;            // 0..4095
        int r = idx >> 6, c = idx & 63;
        xs[r][c] = x[(size_t)(bi * 64 + r) * 64 + c];
        ys[r][c] = y[(size_t)(bj * 64 + r) * 64 + c];
    }
    __syncthreads();

    const int ti0 = (t >> 4) * 4;   // 0..60
    const int tj0 = (t & 15) * 4;   // 0..60
    float acc[4][4] = {};
#pragma unroll 8
    for (int d = 0; d < 64; ++d) {
        float xv[4], yv[4];
#pragma unroll
        for (int k = 0; k < 4; ++k) xv[k] = xs[ti0 + k][d];
#pragma unroll
        for (int l = 0; l < 4; ++l) yv[l] = ys[tj0 + l][d];
#pragma unroll
        for (int k = 0; k < 4; ++k)
#pragma unroll
            for (int l = 0; l < 4; ++l) {
                float df = xv[k] - yv[l];
                acc[k][l] = fmaf(df, df, acc[k][l]);
            }
    }

#pragma unroll
    for (int k = 0; k < 4; ++k) {
        size_t off = (size_t)(bi * 64 + ti0 + k) * NN + bj * 64 + tj0;
        if (c_aligned) {
            *(float4*)(C + off) = make_float4(acc[k][0], acc[k][1], acc[k][2], acc[k][3]);
        } else {  // C lives at out+1 (4B-aligned only)
            C[off + 0] = acc[k][0]; C[off + 1] = acc[k][1];
            C[off + 2] = acc[k][2]; C[off + 3] = acc[k][3];
        }
    }
    if (use_ct) {
#pragma unroll
        for (int l = 0; l < 4; ++l) {
            size_t off = (size_t)(bj * 64 + tj0 + l) * NN + bi * 64 + ti0;
            *(float4*)(CT + off) = make_float4(acc[0][l], acc[1][l], acc[2][l], acc[3][l]);
        }
    }
}

// ---------------------------------------------------------------------------
// Helpers for the main kernel
// ---------------------------------------------------------------------------
__device__ __forceinline__ void load8(const float* row, int t, int aligned, float c[8])
{
    if (aligned) {
        const float4* r4 = (const float4*)row;
        float4 A = r4[t], B = r4[t + 256];
        c[0] = A.x; c[1] = A.y; c[2] = A.z; c[3] = A.w;
        c[4] = B.x; c[5] = B.y; c[6] = B.z; c[7] = B.w;
    } else {
        const float* p = row + 4 * t;
        const float* q = row + 1024 + 4 * t;
        c[0] = p[0]; c[1] = p[1]; c[2] = p[2]; c[3] = p[3];
        c[4] = q[0]; c[5] = q[1]; c[6] = q[2]; c[7] = q[3];
    }
}

// per-thread online max/sum over 8 elements of (b-c)*INV_EPS
__device__ __forceinline__ void lse8(const float c[8], const float b[8],
                                     float& m, float& s)
{
    float a[8];
#pragma unroll
    for (int k = 0; k < 8; ++k) a[k] = (b[k] - c[k]) * INV_EPS;
    m = a[0];
#pragma unroll
    for (int k = 1; k < 8; ++k) m = fmaxf(m, a[k]);
    s = 0.0f;
#pragma unroll
    for (int k = 0; k < 8; ++k) s += __expf(a[k] - m);
}

// block-wide (max,sum) combine; returns lse on thread 0 (others: garbage)
__device__ __forceinline__ float block_lse(float m, float s,
                                           float* red_m, float* red_s, int t)
{
#pragma unroll
    for (int off = 32; off; off >>= 1) {
        float m2 = __shfl_xor(m, off);
        float s2 = __shfl_xor(s, off);
        float nm = fmaxf(m, m2);
        s = __expf(m - nm) * s + __expf(m2 - nm) * s2;
        m = nm;
    }
    int w = t >> 6;
    if ((t & 63) == 0) { red_m[w] = m; red_s[w] = s; }
    __syncthreads();
    float lse = 0.0f;
    if (t == 0) {
        float M = red_m[0], S = red_s[0];
#pragma unroll
        for (int k = 1; k < 4; ++k) {
            float m2 = red_m[k], s2 = red_s[k];
            float nm = fmaxf(M, m2);
            S = __expf(M - nm) * S + __expf(m2 - nm) * s2;
            M = nm;
        }
        lse = M + __logf(S);
    }
    __syncthreads();   // red_* reusable afterwards
    return lse;
}

// ---------------------------------------------------------------------------
// Main cooperative kernel: init, 100 Sinkhorn iterations, pi + cost epilogue.
// NOTE: Cm may alias out+1 (fallback layout) -> no __restrict__ on Cm/out.
// ---------------------------------------------------------------------------
__global__ __launch_bounds__(TPB, 4)
void sinkhorn_main(const float* Cm, const float* __restrict__ CT,
                   float* __restrict__ u0, float* __restrict__ u1,
                   float* __restrict__ v, float* __restrict__ diff,
                   float* __restrict__ cost, float* out,
                   int c_aligned, int use_ct)
{
    cg::grid_group grid = cg::this_grid();
    __shared__ float red_m[4], red_s[4];
    const int t  = threadIdx.x;
    const int b  = blockIdx.x;
    const int nb = gridDim.x;

    // zero u0(2048) | v(2048) | diff(128) | cost(1)  (contiguous from u0)
    for (int idx = b * TPB + t; idx < 2048 + 2048 + 128 + 1; idx += nb * TPB)
        u0[idx] = 0.0f;
    grid.sync();

    float* ucur  = u0;
    float* unext = u1;
    float* ulast = u1;

    for (int it = 0; it < MAX_IT; ++it) {
        // ---- row pass: u_new[i] = eps*(log_a - lse_j((v_j - C_ij)/eps))
        for (int i = b; i < NN; i += nb) {
            float c8[8], b8[8], m, s;
            load8(Cm + (size_t)i * NN, t, c_aligned, c8);
            load8(v, t, 1, b8);
            lse8(c8, b8, m, s);
            float lse = block_lse(m, s, red_m, red_s, t);
            if (t == 0) {
                float un = EPS * (LOG_AB - lse);
                atomicAdd(&diff[it], fabsf(un - ucur[i]));
                unext[i] = un;
            }
        }
        grid.sync();

        // ---- col pass: v_new[j] = eps*(log_b - lse_i((u_i - C_ij)/eps))
        for (int j = b; j < NN; j += nb) {
            float m, s;
            if (use_ct) {
                float c8[8], b8[8];
                load8(CT + (size_t)j * NN, t, 1, c8);
                load8(unext, t, 1, b8);
                lse8(c8, b8, m, s);
            } else {
                // strided fallback (no CT buffer)
                float a[8];
#pragma unroll
                for (int k = 0; k < 8; ++k) {
                    int i2 = t + TPB * k;
                    a[k] = (unext[i2] - Cm[(size_t)i2 * NN + j]) * INV_EPS;
                }
                m = a[0];
#pragma unroll
                for (int k = 1; k < 8; ++k) m = fmaxf(m, a[k]);
                s = 0.0f;
#pragma unroll
                for (int k = 0; k < 8; ++k) s += __expf(a[k] - m);
            }
            float lse = block_lse(m, s, red_m, red_s, t);
            if (t == 0) {
                float vn = EPS * (LOG_AB - lse);
                atomicAdd(&diff[it], fabsf(vn - v[j]));
                v[j] = vn;
            }
        }
        grid.sync();

        ulast = unext;
        if (diff[it] < THRESH) break;      // uniform across grid
        float* tmp = ucur; ucur = unext; unext = tmp;
    }

    // ---- epilogue: pi = exp((u_i + v_j - C_ij)/eps), cost = sum(pi*C)
    const float* uf = ulast;
    float cpart = 0.0f;
    for (int i = b; i < NN; i += nb) {
        float c8[8], b8[8], p8[8];
        load8(Cm + (size_t)i * NN, t, c_aligned, c8);
        load8(v, t, 1, b8);
        float ui = uf[i];
#pragma unroll
        for (int k = 0; k < 8; ++k) {
            p8[k] = __expf((ui + b8[k] - c8[k]) * INV_EPS);
            cpart = fmaf(p8[k], c8[k], cpart);
        }
        // all C-reads of this row consumed above; barrier before in-place
        // overwrite (Cm may alias out+1, same-row overlap only)
        __syncthreads();
        float* orow = out + 1 + (size_t)i * NN;
#pragma unroll
        for (int k = 0; k < 8; ++k) {
            int col = (k < 4) ? (4 * t + k) : (1024 + 4 * t + (k - 4));
            orow[col] = p8[k];
        }
        __syncthreads();
    }
#pragma unroll
    for (int off = 32; off; off >>= 1) cpart += __shfl_xor(cpart, off);
    if ((t & 63) == 0) red_s[t >> 6] = cpart;
    __syncthreads();
    if (t == 0) atomicAdd(cost, red_s[0] + red_s[1] + red_s[2] + red_s[3]);
    grid.sync();
    if (b == 0 && t == 0) out[0] = *cost;
}

// ---------------------------------------------------------------------------
extern "C" void kernel_launch(void* const* d_in, const int* in_sizes, int n_in,
                              void* d_out, int out_size, void* d_ws, size_t ws_size,
                              hipStream_t stream)
{
    (void)in_sizes; (void)n_in; (void)out_size;
    const float* x = (const float*)d_in[0];
    const float* y = (const float*)d_in[1];
    float* out = (float*)d_out;
    char*  ws  = (char*)d_ws;

    const size_t CB = (size_t)NN * NN * sizeof(float);   // 16 MiB
    const size_t ZZ = 64 * 1024;

    float *Cm, *CT, *zz;
    int c_aligned, use_ct;
    if (ws_size >= 2 * CB + ZZ) {             // preferred: C, CT, state in ws
        Cm = (float*)ws; CT = (float*)(ws + CB); zz = (float*)(ws + 2 * CB);
        c_aligned = 1; use_ct = 1;
    } else if (ws_size >= CB + ZZ) {          // C in out+1, CT in ws
        Cm = out + 1; CT = (float*)ws; zz = (float*)(ws + CB);
        c_aligned = 0; use_ct = 1;
    } else {                                  // C in out+1, no CT (strided)
        Cm = out + 1; CT = nullptr; zz = (float*)ws;
        c_aligned = 0; use_ct = 0;
    }
    float* u0   = zz;
    float* v    = zz + 2048;
    float* diff = zz + 4096;
    float* cost = zz + 4224;
    float* u1   = zz + 4352;   // 16B-aligned (4352*4 % 16 == 0)

    hipLaunchKernelGGL(build_cost, dim3(32, 32), dim3(TPB), 0, stream,
                       x, y, Cm, CT, c_aligned, use_ct);

    int dev = 0;
    hipGetDevice(&dev);
    int numCU = 256;
    hipDeviceGetAttribute(&numCU, hipDeviceAttributeMultiprocessorCount, dev);
    int occ = 0;
    hipOccupancyMaxActiveBlocksPerMultiprocessor(&occ, sinkhorn_main, TPB, 0);
    if (occ < 1) occ = 1;
    long nb = (long)numCU * occ;
    if (nb > 1024) nb = 1024;

    const float* Cmc = Cm;
    const float* CTc = CT;
    void* args[] = { (void*)&Cmc, (void*)&CTc, (void*)&u0, (void*)&u1,
                     (void*)&v, (void*)&diff, (void*)&cost, (void*)&out,
                     (void*)&c_aligned, (void*)&use_ct };
    hipLaunchCooperativeKernel((void*)sinkhorn_main, dim3((int)nb), dim3(TPB),
                               args, 0, stream);
}

// Round 2
// 2807.906 us; speedup vs baseline: 6.3022x; 6.3022x over previous
//
#include <hip/hip_runtime.h>
#include <cstddef>

static constexpr int   NN      = 2048;
static constexpr int   TPB_B   = 256;   // build_cost block
static constexpr int   TPB     = 512;   // main kernel block (8 waves)
static constexpr int   NWB     = TPB / 64;
static constexpr int   MAX_IT  = 100;
static constexpr float EPS     = 0.1f;
static constexpr float INV_EPS = 10.0f;
// logf(1/2048 + 1e-8)
static constexpr float LOG_AB  = -7.6245985063594f;
static constexpr float THRESH  = 0.1f;

// ---------------------------------------------------------------------------
// Cost matrix build + state zeroing. C[i][j] = sum_d (x[i,d]-y[j,d])^2.
// 64x64 tile/block, LDS-staged x/y, 4x4 register tile/thread.
// ---------------------------------------------------------------------------
__global__ __launch_bounds__(TPB_B)
void build_cost(const float* __restrict__ x, const float* __restrict__ y,
                float* __restrict__ C, float* __restrict__ CT,
                float* __restrict__ zz, int c_aligned, int use_ct)
{
    __shared__ float xs[64][65];
    __shared__ float ys[64][65];
    const int t  = threadIdx.x;
    const int bi = blockIdx.y, bj = blockIdx.x;

    // block (0,0) zeroes state: u0(2048) v(2048) diff(100..) cost cnt  < 4352
    if (bi == 0 && bj == 0)
        for (int idx = t; idx < 4352; idx += TPB_B) zz[idx] = 0.0f;

#pragma unroll
    for (int k = 0; k < 16; ++k) {
        int idx = t + TPB_B * k;
        int r = idx >> 6, c = idx & 63;
        xs[r][c] = x[(size_t)(bi * 64 + r) * 64 + c];
        ys[r][c] = y[(size_t)(bj * 64 + r) * 64 + c];
    }
    __syncthreads();

    const int ti0 = (t >> 4) * 4;
    const int tj0 = (t & 15) * 4;
    float acc[4][4] = {};
#pragma unroll 8
    for (int d = 0; d < 64; ++d) {
        float xv[4], yv[4];
#pragma unroll
        for (int k = 0; k < 4; ++k) xv[k] = xs[ti0 + k][d];
#pragma unroll
        for (int l = 0; l < 4; ++l) yv[l] = ys[tj0 + l][d];
#pragma unroll
        for (int k = 0; k < 4; ++k)
#pragma unroll
            for (int l = 0; l < 4; ++l) {
                float df = xv[k] - yv[l];
                acc[k][l] = fmaf(df, df, acc[k][l]);
            }
    }

#pragma unroll
    for (int k = 0; k < 4; ++k) {
        size_t off = (size_t)(bi * 64 + ti0 + k) * NN + bj * 64 + tj0;
        if (c_aligned) {
            *(float4*)(C + off) = make_float4(acc[k][0], acc[k][1], acc[k][2], acc[k][3]);
        } else {
            C[off + 0] = acc[k][0]; C[off + 1] = acc[k][1];
            C[off + 2] = acc[k][2]; C[off + 3] = acc[k][3];
        }
    }
    if (use_ct) {
#pragma unroll
        for (int l = 0; l < 4; ++l) {
            size_t off = (size_t)(bj * 64 + tj0 + l) * NN + bi * 64 + ti0;
            *(float4*)(CT + off) = make_float4(acc[0][l], acc[1][l], acc[2][l], acc[3][l]);
        }
    }
}

// ---------------------------------------------------------------------------
// Helpers
// ---------------------------------------------------------------------------
__device__ __forceinline__ void load_row32(const float* row, int lane,
                                           int aligned, float c[32])
{
    if (aligned) {
        const float4* r4 = (const float4*)row;
#pragma unroll
        for (int k = 0; k < 8; ++k) {
            float4 A = r4[lane + 64 * k];
            c[4*k+0] = A.x; c[4*k+1] = A.y; c[4*k+2] = A.z; c[4*k+3] = A.w;
        }
    } else {
#pragma unroll
        for (int k = 0; k < 8; ++k) {
            const float* p = row + 4 * (lane + 64 * k);
            c[4*k+0] = p[0]; c[4*k+1] = p[1]; c[4*k+2] = p[2]; c[4*k+3] = p[3];
        }
    }
}

// wave-level lse of (b-c)*INV_EPS over 2048 elems (32/lane); result on all lanes
__device__ __forceinline__ float wave_lse(float c[32], const float b[32])
{
#pragma unroll
    for (int k = 0; k < 32; ++k) c[k] = (b[k] - c[k]) * INV_EPS;
    float m = c[0];
#pragma unroll
    for (int k = 1; k < 32; ++k) m = fmaxf(m, c[k]);
    float s = 0.0f;
#pragma unroll
    for (int k = 0; k < 32; ++k) s += __expf(c[k] - m);
#pragma unroll
    for (int off = 1; off < 64; off <<= 1) {
        float m2 = __shfl_xor(m, off);
        float s2 = __shfl_xor(s, off);
        float nm = fmaxf(m, m2);
        s = __expf(m - nm) * s + __expf(m2 - nm) * s2;
        m = nm;
    }
    return m + __logf(s);
}

// grid barrier: monotonic counter, relaxed spin, one acquire fence
__device__ __forceinline__ void gbar(unsigned* cnt, unsigned target)
{
    __syncthreads();
    if (threadIdx.x == 0) {
        __builtin_amdgcn_fence(__ATOMIC_RELEASE, "agent");
        __hip_atomic_fetch_add(cnt, 1u, __ATOMIC_RELAXED, __HIP_MEMORY_SCOPE_AGENT);
        while (__hip_atomic_load(cnt, __ATOMIC_RELAXED, __HIP_MEMORY_SCOPE_AGENT) < target)
            __builtin_amdgcn_s_sleep(2);
        __builtin_amdgcn_fence(__ATOMIC_ACQUIRE, "agent");
    }
    __syncthreads();
}

// ---------------------------------------------------------------------------
// Main cooperative kernel. Wave-per-row/col. Cm may alias out+1.
// ---------------------------------------------------------------------------
__global__ __launch_bounds__(TPB, 2)
void sinkhorn_main(const float* Cm, const float* __restrict__ CT,
                   float* __restrict__ u0, float* __restrict__ u1,
                   float* __restrict__ v, float* __restrict__ diff,
                   float* __restrict__ cost, unsigned* __restrict__ cnt,
                   float* out, int c_aligned, int use_ct)
{
    __shared__ float sdiff, scost;
    const int t      = threadIdx.x;
    const int lane   = t & 63;
    const int w      = t >> 6;
    const int b      = blockIdx.x;
    const int nb     = gridDim.x;
    const int wid0   = b * NWB + w;
    const int nwaves = nb * NWB;

    unsigned target = 0;

    float* ucur  = u0;
    float* unext = u1;
    float* ulast = u1;

    for (int it = 0; it < MAX_IT; ++it) {
        if (t == 0) sdiff = 0.0f;
        __syncthreads();

        // ---- row pass: u_new[i] = eps*(log_a - lse_j((v_j - C_ij)/eps))
        for (int i = wid0; i < NN; i += nwaves) {
            float c32[32], b32[32];
            load_row32(Cm + (size_t)i * NN, lane, c_aligned, c32);
            load_row32(v, lane, 1, b32);
            float lse = wave_lse(c32, b32);
            if (lane == 0) {
                float un = EPS * (LOG_AB - lse);
                atomicAdd(&sdiff, fabsf(un - ucur[i]));
                unext[i] = un;
            }
        }
        target += nb; gbar(cnt, target);

        // ---- col pass: v_new[j] = eps*(log_b - lse_i((u_i - C_ij)/eps))
        for (int j = wid0; j < NN; j += nwaves) {
            float lse;
            float b32[32];
            load_row32(unext, lane, 1, b32);
            if (use_ct) {
                float c32[32];
                load_row32(CT + (size_t)j * NN, lane, 1, c32);
                lse = wave_lse(c32, b32);
            } else {
                float c32[32];   // strided fallback
#pragma unroll
                for (int k = 0; k < 32; ++k)
                    c32[k] = Cm[(size_t)(lane + 64 * (k >> 2) * 4 + (k & 3) * 64) * NN + j];
                // note: index above must match b32 order: elem e = 4*(lane+64k)+kk
#pragma unroll
                for (int k = 0; k < 8; ++k)
#pragma unroll
                    for (int kk = 0; kk < 4; ++kk)
                        c32[4*k+kk] = Cm[(size_t)(4 * (lane + 64 * k) + kk) * NN + j];
                lse = wave_lse(c32, b32);
            }
            if (lane == 0) {
                float vn = EPS * (LOG_AB - lse);
                atomicAdd(&sdiff, fabsf(vn - v[j]));
                v[j] = vn;
            }
        }
        __syncthreads();
        if (t == 0) atomicAdd(&diff[it], sdiff);
        target += nb; gbar(cnt, target);

        ulast = unext;
        if (diff[it] < THRESH) break;        // uniform across grid
        float* tmp = ucur; ucur = unext; unext = tmp;
    }

    // ---- epilogue: pi = exp((u_i + v_j - C_ij)/eps), cost = sum(pi*C)
    const float* uf = ulast;
    float cpart = 0.0f;
    for (int i = wid0; i < NN; i += nwaves) {
        float c32[32], b32[32];
        load_row32(Cm + (size_t)i * NN, lane, c_aligned, c32);
        load_row32(v, lane, 1, b32);
        float ui = uf[i];
        float* orow = out + 1 + (size_t)i * NN;
#pragma unroll
        for (int k = 0; k < 8; ++k) {
#pragma unroll
            for (int kk = 0; kk < 4; ++kk) {
                float cc = c32[4*k+kk];
                float p  = __expf((ui + b32[4*k+kk] - cc) * INV_EPS);
                cpart = fmaf(p, cc, cpart);
                orow[4 * (lane + 64 * k) + kk] = p;   // safe even if Cm==out+1
            }
        }
    }
#pragma unroll
    for (int off = 1; off < 64; off <<= 1) cpart += __shfl_xor(cpart, off);
    if (t == 0) scost = 0.0f;
    __syncthreads();
    if (lane == 0) atomicAdd(&scost, cpart);
    __syncthreads();
    if (t == 0) atomicAdd(cost, scost);
    target += nb; gbar(cnt, target);
    if (b == 0 && t == 0) out[0] = *cost;
}

// ---------------------------------------------------------------------------
extern "C" void kernel_launch(void* const* d_in, const int* in_sizes, int n_in,
                              void* d_out, int out_size, void* d_ws, size_t ws_size,
                              hipStream_t stream)
{
    (void)in_sizes; (void)n_in; (void)out_size;
    const float* x = (const float*)d_in[0];
    const float* y = (const float*)d_in[1];
    float* out = (float*)d_out;
    char*  ws  = (char*)d_ws;

    const size_t CB = (size_t)NN * NN * sizeof(float);   // 16 MiB
    const size_t ZZ = 64 * 1024;

    float *Cm, *CT, *zz;
    int c_aligned, use_ct;
    if (ws_size >= 2 * CB + ZZ) {             // preferred: C, CT, state in ws
        Cm = (float*)ws; CT = (float*)(ws + CB); zz = (float*)(ws + 2 * CB);
        c_aligned = 1; use_ct = 1;
    } else if (ws_size >= CB + ZZ) {          // C in out+1, CT in ws
        Cm = out + 1; CT = (float*)ws; zz = (float*)(ws + CB);
        c_aligned = 0; use_ct = 1;
    } else {                                  // C in out+1, no CT (strided)
        Cm = out + 1; CT = nullptr; zz = (float*)ws;
        c_aligned = 0; use_ct = 0;
    }
    float*    u0   = zz;
    float*    v    = zz + 2048;
    float*    diff = zz + 4096;
    float*    cost = zz + 4224;
    unsigned* cnt  = (unsigned*)(zz + 4228);
    float*    u1   = zz + 4352;   // 16B-aligned

    hipLaunchKernelGGL(build_cost, dim3(32, 32), dim3(TPB_B), 0, stream,
                       x, y, Cm, CT, zz, c_aligned, use_ct);

    int dev = 0;
    hipGetDevice(&dev);
    int numCU = 256;
    hipDeviceGetAttribute(&numCU, hipDeviceAttributeMultiprocessorCount, dev);
    int occ = 0;
    hipOccupancyMaxActiveBlocksPerMultiprocessor(&occ, sinkhorn_main, TPB, 0);
    if (occ < 1) occ = 1;
    long nb = (long)numCU * occ;
    if (nb > 256) nb = 256;

    const float* Cmc = Cm;
    const float* CTc = CT;
    void* args[] = { (void*)&Cmc, (void*)&CTc, (void*)&u0, (void*)&u1,
                     (void*)&v, (void*)&diff, (void*)&cost, (void*)&cnt,
                     (void*)&out, (void*)&c_aligned, (void*)&use_ct };
    hipLaunchCooperativeKernel((void*)sinkhorn_main, dim3((int)nb), dim3(TPB),
                               args, 0, stream);
}

// Round 3
// 1971.875 us; speedup vs baseline: 8.9742x; 1.4240x over previous
//
#include <hip/hip_runtime.h>
#include <cstddef>

static constexpr int   NN      = 2048;
static constexpr int   TPB_B   = 256;   // build_cost block
static constexpr int   TPB     = 512;   // main kernel block (8 waves)
static constexpr int   NWB     = TPB / 64;          // 8 waves/block
static constexpr int   NB      = 64;                // main grid blocks
static constexpr int   NWAVES  = NB * NWB;          // 512 waves
static constexpr int   RPW     = NN / NWAVES;       // 4 rows per wave
static constexpr int   MAX_IT  = 100;
static constexpr float EPS     = 0.1f;
static constexpr float INV_EPS = 10.0f;
// logf(1/2048 + 1e-8)
static constexpr float LOG_AB  = -7.6245985063594f;
static constexpr float THRESH  = 0.1f;

// ---------------------------------------------------------------------------
// Cost matrix build + state zeroing. C[i][j] = sum_d (x[i,d]-y[j,d])^2.
// ---------------------------------------------------------------------------
__global__ __launch_bounds__(TPB_B)
void build_cost(const float* __restrict__ x, const float* __restrict__ y,
                float* __restrict__ C, float* __restrict__ CT,
                float* __restrict__ zz, int c_aligned, int use_ct)
{
    __shared__ float xs[64][65];
    __shared__ float ys[64][65];
    const int t  = threadIdx.x;
    const int bi = blockIdx.y, bj = blockIdx.x;

    // block (0,0) zeroes state: u0|v|diff|cost|cnt|flag all in [0,4352)
    if (bi == 0 && bj == 0)
        for (int idx = t; idx < 4352; idx += TPB_B) zz[idx] = 0.0f;

#pragma unroll
    for (int k = 0; k < 16; ++k) {
        int idx = t + TPB_B * k;
        int r = idx >> 6, c = idx & 63;
        xs[r][c] = x[(size_t)(bi * 64 + r) * 64 + c];
        ys[r][c] = y[(size_t)(bj * 64 + r) * 64 + c];
    }
    __syncthreads();

    const int ti0 = (t >> 4) * 4;
    const int tj0 = (t & 15) * 4;
    float acc[4][4] = {};
#pragma unroll 8
    for (int d = 0; d < 64; ++d) {
        float xv[4], yv[4];
#pragma unroll
        for (int k = 0; k < 4; ++k) xv[k] = xs[ti0 + k][d];
#pragma unroll
        for (int l = 0; l < 4; ++l) yv[l] = ys[tj0 + l][d];
#pragma unroll
        for (int k = 0; k < 4; ++k)
#pragma unroll
            for (int l = 0; l < 4; ++l) {
                float df = xv[k] - yv[l];
                acc[k][l] = fmaf(df, df, acc[k][l]);
            }
    }

#pragma unroll
    for (int k = 0; k < 4; ++k) {
        size_t off = (size_t)(bi * 64 + ti0 + k) * NN + bj * 64 + tj0;
        if (c_aligned) {
            *(float4*)(C + off) = make_float4(acc[k][0], acc[k][1], acc[k][2], acc[k][3]);
        } else {
            C[off + 0] = acc[k][0]; C[off + 1] = acc[k][1];
            C[off + 2] = acc[k][2]; C[off + 3] = acc[k][3];
        }
    }
    if (use_ct) {
#pragma unroll
        for (int l = 0; l < 4; ++l) {
            size_t off = (size_t)(bj * 64 + tj0 + l) * NN + bi * 64 + ti0;
            *(float4*)(CT + off) = make_float4(acc[0][l], acc[1][l], acc[2][l], acc[3][l]);
        }
    }
}

// ---------------------------------------------------------------------------
// Helpers
// ---------------------------------------------------------------------------
__device__ __forceinline__ void load_row32(const float* row, int lane,
                                           int aligned, float c[32])
{
    if (aligned) {
        const float4* r4 = (const float4*)row;
#pragma unroll
        for (int k = 0; k < 8; ++k) {
            float4 A = r4[lane + 64 * k];
            c[4*k+0] = A.x; c[4*k+1] = A.y; c[4*k+2] = A.z; c[4*k+3] = A.w;
        }
    } else {
#pragma unroll
        for (int k = 0; k < 8; ++k) {
            const float* p = row + 4 * (lane + 64 * k);
            c[4*k+0] = p[0]; c[4*k+1] = p[1]; c[4*k+2] = p[2]; c[4*k+3] = p[3];
        }
    }
}

// wave-level lse of (b-c)*INV_EPS over 2048 elems (32/lane); result on all lanes
__device__ __forceinline__ float wave_lse(float c[32], const float b[32])
{
#pragma unroll
    for (int k = 0; k < 32; ++k) c[k] = (b[k] - c[k]) * INV_EPS;
    float m = c[0];
#pragma unroll
    for (int k = 1; k < 32; ++k) m = fmaxf(m, c[k]);
    float s = 0.0f;
#pragma unroll
    for (int k = 0; k < 32; ++k) s += __expf(c[k] - m);
#pragma unroll
    for (int off = 1; off < 64; off <<= 1) {
        float m2 = __shfl_xor(m, off);
        float s2 = __shfl_xor(s, off);
        float nm = fmaxf(m, m2);
        s = __expf(m - nm) * s + __expf(m2 - nm) * s2;
        m = nm;
    }
    return m + __logf(s);
}

// grid barrier: arrival counter and release flag on SEPARATE cache lines.
// Monotonic epochs (bar = k*NB), no reset needed.
__device__ __forceinline__ void gbar(unsigned* cnt, unsigned* flag, unsigned bar)
{
    __syncthreads();
    if (threadIdx.x == 0) {
        __builtin_amdgcn_fence(__ATOMIC_RELEASE, "agent");
        unsigned old = __hip_atomic_fetch_add(cnt, 1u, __ATOMIC_RELAXED,
                                              __HIP_MEMORY_SCOPE_AGENT);
        if (old == bar - 1u) {   // last arriver: publish release epoch
            __builtin_amdgcn_fence(__ATOMIC_ACQUIRE, "agent");
            __hip_atomic_store(flag, bar, __ATOMIC_RELEASE,
                               __HIP_MEMORY_SCOPE_AGENT);
        } else {
            while (__hip_atomic_load(flag, __ATOMIC_RELAXED,
                                     __HIP_MEMORY_SCOPE_AGENT) < bar)
                __builtin_amdgcn_s_sleep(1);
            __builtin_amdgcn_fence(__ATOMIC_ACQUIRE, "agent");
        }
    }
    __syncthreads();
}

// ---------------------------------------------------------------------------
// Main cooperative kernel. 64 blocks x 512 thr; 4 rows per wave per pass.
// Cm may alias out+1.
// ---------------------------------------------------------------------------
__global__ __launch_bounds__(TPB)
void sinkhorn_main(const float* Cm, const float* __restrict__ CT,
                   float* __restrict__ u0, float* __restrict__ u1,
                   float* __restrict__ v, float* __restrict__ diff,
                   float* __restrict__ cost,
                   unsigned* __restrict__ cnt, unsigned* __restrict__ flag,
                   float* out, int c_aligned, int use_ct)
{
    __shared__ float sdiff, scost;
    const int t    = threadIdx.x;
    const int lane = t & 63;
    const int w    = t >> 6;
    const int b    = blockIdx.x;
    const int wid0 = b * NWB + w;

    unsigned bar = 0;

    float* ucur  = u0;
    float* unext = u1;
    float* ulast = u1;

    for (int it = 0; it < MAX_IT; ++it) {
        if (t == 0) sdiff = 0.0f;
        __syncthreads();

        // ---- row pass: u_new[i] = eps*(log_a - lse_j((v_j - C_ij)/eps))
        {
            float b32[32];
            load_row32(v, lane, 1, b32);
#pragma unroll
            for (int r = 0; r < RPW; r += 2) {      // pairwise for load overlap
                int iA = wid0 + (r + 0) * NWAVES;
                int iB = wid0 + (r + 1) * NWAVES;
                float cA[32], cB[32];
                load_row32(Cm + (size_t)iA * NN, lane, c_aligned, cA);
                load_row32(Cm + (size_t)iB * NN, lane, c_aligned, cB);
                float lseA = wave_lse(cA, b32);
                float lseB = wave_lse(cB, b32);
                if (lane == 0) {
                    float unA = EPS * (LOG_AB - lseA);
                    float unB = EPS * (LOG_AB - lseB);
                    atomicAdd(&sdiff, fabsf(unA - ucur[iA]) + fabsf(unB - ucur[iB]));
                    unext[iA] = unA;
                    unext[iB] = unB;
                }
            }
        }
        bar += NB; gbar(cnt, flag, bar);

        // ---- col pass: v_new[j] = eps*(log_b - lse_i((u_i - C_ij)/eps))
        {
            float b32[32];
            load_row32(unext, lane, 1, b32);
#pragma unroll
            for (int r = 0; r < RPW; r += 2) {
                int jA = wid0 + (r + 0) * NWAVES;
                int jB = wid0 + (r + 1) * NWAVES;
                float lseA, lseB;
                if (use_ct) {
                    float cA[32], cB[32];
                    load_row32(CT + (size_t)jA * NN, lane, 1, cA);
                    load_row32(CT + (size_t)jB * NN, lane, 1, cB);
                    lseA = wave_lse(cA, b32);
                    lseB = wave_lse(cB, b32);
                } else {
                    float cA[32], cB[32];   // strided fallback
#pragma unroll
                    for (int k = 0; k < 8; ++k)
#pragma unroll
                        for (int kk = 0; kk < 4; ++kk) {
                            size_t i2 = (size_t)(4 * (lane + 64 * k) + kk) * NN;
                            cA[4*k+kk] = Cm[i2 + jA];
                            cB[4*k+kk] = Cm[i2 + jB];
                        }
                    lseA = wave_lse(cA, b32);
                    lseB = wave_lse(cB, b32);
                }
                if (lane == 0) {
                    float vnA = EPS * (LOG_AB - lseA);
                    float vnB = EPS * (LOG_AB - lseB);
                    atomicAdd(&sdiff, fabsf(vnA - v[jA]) + fabsf(vnB - v[jB]));
                    v[jA] = vnA;
                    v[jB] = vnB;
                }
            }
        }
        __syncthreads();
        if (t == 0) atomicAdd(&diff[it], sdiff);
        bar += NB; gbar(cnt, flag, bar);

        ulast = unext;
        if (diff[it] < THRESH) break;        // uniform across grid
        float* tmp = ucur; ucur = unext; unext = tmp;
    }

    // ---- epilogue: pi = exp((u_i + v_j - C_ij)/eps), cost = sum(pi*C)
    const float* uf = ulast;
    float cpart = 0.0f;
    {
        float b32[32];
        load_row32(v, lane, 1, b32);
#pragma unroll
        for (int r = 0; r < RPW; ++r) {
            int i = wid0 + r * NWAVES;
            float c32[32];
            load_row32(Cm + (size_t)i * NN, lane, c_aligned, c32);
            float ui = uf[i];
            float* orow = out + 1 + (size_t)i * NN;
#pragma unroll
            for (int k = 0; k < 8; ++k) {
#pragma unroll
                for (int kk = 0; kk < 4; ++kk) {
                    float cc = c32[4*k+kk];
                    float p  = __expf((ui + b32[4*k+kk] - cc) * INV_EPS);
                    cpart = fmaf(p, cc, cpart);
                    orow[4 * (lane + 64 * k) + kk] = p;  // safe even if Cm==out+1
                }
            }
        }
    }
#pragma unroll
    for (int off = 1; off < 64; off <<= 1) cpart += __shfl_xor(cpart, off);
    if (t == 0) scost = 0.0f;
    __syncthreads();
    if (lane == 0) atomicAdd(&scost, cpart);
    __syncthreads();
    if (t == 0) atomicAdd(cost, scost);
    bar += NB; gbar(cnt, flag, bar);
    if (b == 0 && t == 0) out[0] = *cost;
}

// ---------------------------------------------------------------------------
extern "C" void kernel_launch(void* const* d_in, const int* in_sizes, int n_in,
                              void* d_out, int out_size, void* d_ws, size_t ws_size,
                              hipStream_t stream)
{
    (void)in_sizes; (void)n_in; (void)out_size;
    const float* x = (const float*)d_in[0];
    const float* y = (const float*)d_in[1];
    float* out = (float*)d_out;
    char*  ws  = (char*)d_ws;

    const size_t CB = (size_t)NN * NN * sizeof(float);   // 16 MiB
    const size_t ZZ = 64 * 1024;

    float *Cm, *CT, *zz;
    int c_aligned, use_ct;
    if (ws_size >= 2 * CB + ZZ) {             // preferred: C, CT, state in ws
        Cm = (float*)ws; CT = (float*)(ws + CB); zz = (float*)(ws + 2 * CB);
        c_aligned = 1; use_ct = 1;
    } else if (ws_size >= CB + ZZ) {          // C in out+1, CT in ws
        Cm = out + 1; CT = (float*)ws; zz = (float*)(ws + CB);
        c_aligned = 0; use_ct = 1;
    } else {                                  // C in out+1, no CT (strided)
        Cm = out + 1; CT = nullptr; zz = (float*)ws;
        c_aligned = 0; use_ct = 0;
    }
    float*    u0   = zz;
    float*    v    = zz + 2048;
    float*    diff = zz + 4096;          // 100 floats used
    float*    cost = zz + 4224;
    unsigned* cnt  = (unsigned*)(zz + 4256);  // own 128B line
    unsigned* flag = (unsigned*)(zz + 4288);  // own 128B line
    float*    u1   = zz + 4352;          // 16B-aligned

    hipLaunchKernelGGL(build_cost, dim3(32, 32), dim3(TPB_B), 0, stream,
                       x, y, Cm, CT, zz, c_aligned, use_ct);

    const float* Cmc = Cm;
    const float* CTc = CT;
    void* args[] = { (void*)&Cmc, (void*)&CTc, (void*)&u0, (void*)&u1,
                     (void*)&v, (void*)&diff, (void*)&cost,
                     (void*)&cnt, (void*)&flag,
                     (void*)&out, (void*)&c_aligned, (void*)&use_ct };
    hipLaunchCooperativeKernel((void*)sinkhorn_main, dim3(NB), dim3(TPB),
                               args, 0, stream);
}

// Round 4
// 1600.408 us; speedup vs baseline: 11.0572x; 1.2321x over previous
//
#include <hip/hip_runtime.h>
#include <cstddef>

static constexpr int   NN      = 2048;
static constexpr int   TPB_B   = 256;   // build_cost block
static constexpr int   TPB     = 512;   // main kernel block (8 waves)
static constexpr int   NWB     = TPB / 64;          // 8 waves/block
static constexpr int   NB      = 128;               // main grid blocks
static constexpr int   NWAVES  = NB * NWB;          // 1024 waves
static constexpr int   RPW     = NN / NWAVES;       // 2 rows per wave
static constexpr int   SLOTSTR = 16;                // u64 stride: 1 slot / 128B line
static constexpr int   MAX_IT  = 100;
static constexpr float EPS     = 0.1f;
static constexpr float INV_EPS = 10.0f;
// logf(1/2048 + 1e-8)
static constexpr float LOG_AB  = -7.6245985063594f;
static constexpr float THRESH  = 0.1f;

// ---------------------------------------------------------------------------
// Cost matrix build + state zeroing. C[i][j] = sum_d (x[i,d]-y[j,d])^2.
// ---------------------------------------------------------------------------
__global__ __launch_bounds__(TPB_B)
void build_cost(const float* __restrict__ x, const float* __restrict__ y,
                float* __restrict__ C, float* __restrict__ CT,
                float* __restrict__ zz, int c_aligned, int use_ct)
{
    __shared__ float xs[64][65];
    __shared__ float ys[64][65];
    const int t  = threadIdx.x;
    const int bi = blockIdx.y, bj = blockIdx.x;

    // block (0,0) zeroes state: u0[0,2048) v[2048,4096) slots[4096,8192)
    if (bi == 0 && bj == 0)
        for (int idx = t; idx < 8192; idx += TPB_B) zz[idx] = 0.0f;

#pragma unroll
    for (int k = 0; k < 16; ++k) {
        int idx = t + TPB_B * k;
        int r = idx >> 6, c = idx & 63;
        xs[r][c] = x[(size_t)(bi * 64 + r) * 64 + c];
        ys[r][c] = y[(size_t)(bj * 64 + r) * 64 + c];
    }
    __syncthreads();

    const int ti0 = (t >> 4) * 4;
    const int tj0 = (t & 15) * 4;
    float acc[4][4] = {};
#pragma unroll 8
    for (int d = 0; d < 64; ++d) {
        float xv[4], yv[4];
#pragma unroll
        for (int k = 0; k < 4; ++k) xv[k] = xs[ti0 + k][d];
#pragma unroll
        for (int l = 0; l < 4; ++l) yv[l] = ys[tj0 + l][d];
#pragma unroll
        for (int k = 0; k < 4; ++k)
#pragma unroll
            for (int l = 0; l < 4; ++l) {
                float df = xv[k] - yv[l];
                acc[k][l] = fmaf(df, df, acc[k][l]);
            }
    }

#pragma unroll
    for (int k = 0; k < 4; ++k) {
        size_t off = (size_t)(bi * 64 + ti0 + k) * NN + bj * 64 + tj0;
        if (c_aligned) {
            *(float4*)(C + off) = make_float4(acc[k][0], acc[k][1], acc[k][2], acc[k][3]);
        } else {
            C[off + 0] = acc[k][0]; C[off + 1] = acc[k][1];
            C[off + 2] = acc[k][2]; C[off + 3] = acc[k][3];
        }
    }
    if (use_ct) {
#pragma unroll
        for (int l = 0; l < 4; ++l) {
            size_t off = (size_t)(bj * 64 + tj0 + l) * NN + bi * 64 + ti0;
            *(float4*)(CT + off) = make_float4(acc[0][l], acc[1][l], acc[2][l], acc[3][l]);
        }
    }
}

// ---------------------------------------------------------------------------
// Helpers
// ---------------------------------------------------------------------------
__device__ __forceinline__ void load_row32(const float* row, int lane,
                                           int aligned, float c[32])
{
    if (aligned) {
        const float4* r4 = (const float4*)row;
#pragma unroll
        for (int k = 0; k < 8; ++k) {
            float4 A = r4[lane + 64 * k];
            c[4*k+0] = A.x; c[4*k+1] = A.y; c[4*k+2] = A.z; c[4*k+3] = A.w;
        }
    } else {
#pragma unroll
        for (int k = 0; k < 8; ++k) {
            const float* p = row + 4 * (lane + 64 * k);
            c[4*k+0] = p[0]; c[4*k+1] = p[1]; c[4*k+2] = p[2]; c[4*k+3] = p[3];
        }
    }
}

// wave-level lse of (b-c)*INV_EPS over 2048 elems (32/lane); result on all lanes
__device__ __forceinline__ float wave_lse(float c[32], const float b[32])
{
#pragma unroll
    for (int k = 0; k < 32; ++k) c[k] = (b[k] - c[k]) * INV_EPS;
    float m = c[0];
#pragma unroll
    for (int k = 1; k < 32; ++k) m = fmaxf(m, c[k]);
    float s = 0.0f;
#pragma unroll
    for (int k = 0; k < 32; ++k) s += __expf(c[k] - m);
#pragma unroll
    for (int off = 1; off < 64; off <<= 1) {
        float m2 = __shfl_xor(m, off);
        float s2 = __shfl_xor(s, off);
        float nm = fmaxf(m, m2);
        s = __expf(m - nm) * s + __expf(m2 - nm) * s2;
        m = nm;
    }
    return m + __logf(s);
}

// ---------------------------------------------------------------------------
// Slot barrier: NO same-address RMW anywhere.
// Block b release-stores {epoch:u32 | pdiff:f32} into its own cache line;
// wave 0 of every block polls all NB slots lane-parallel (2 slots/lane) and
// reduces the NB pdiffs while it's at it. Returns sum of pdiffs to all threads.
// ---------------------------------------------------------------------------
__device__ __forceinline__ float gbar(unsigned long long* slots, unsigned epoch,
                                      const float* swave, float* sred)
{
    const int t = threadIdx.x;
    __syncthreads();                              // pass complete, swave ready
    if (t < 64) {
        if (t == 0) {
            float pdiff = 0.0f;
#pragma unroll
            for (int w = 0; w < NWB; ++w) pdiff += swave[w];
            unsigned long long val = ((unsigned long long)epoch << 32) |
                                     (unsigned long long)__float_as_uint(pdiff);
            __builtin_amdgcn_fence(__ATOMIC_RELEASE, "agent");
            __hip_atomic_store(&slots[(size_t)blockIdx.x * SLOTSTR], val,
                               __ATOMIC_RELAXED, __HIP_MEMORY_SCOPE_AGENT);
        }
        unsigned long long v0, v1;
        for (;;) {
            v0 = __hip_atomic_load(&slots[(size_t)(2 * t + 0) * SLOTSTR],
                                   __ATOMIC_RELAXED, __HIP_MEMORY_SCOPE_AGENT);
            v1 = __hip_atomic_load(&slots[(size_t)(2 * t + 1) * SLOTSTR],
                                   __ATOMIC_RELAXED, __HIP_MEMORY_SCOPE_AGENT);
            bool ok = ((unsigned)(v0 >> 32) >= epoch) &&
                      ((unsigned)(v1 >> 32) >= epoch);
            if (__ballot(ok) == ~0ull) break;
            __builtin_amdgcn_s_sleep(2);
        }
        __builtin_amdgcn_fence(__ATOMIC_ACQUIRE, "agent");
        float d = __uint_as_float((unsigned)v0) + __uint_as_float((unsigned)v1);
#pragma unroll
        for (int off = 1; off < 64; off <<= 1) d += __shfl_xor(d, off);
        if (t == 0) *sred = d;
    }
    __syncthreads();
    return *sred;
}

// ---------------------------------------------------------------------------
// Main cooperative kernel. 128 blocks x 512 thr; 2 rows per wave per pass.
// Cm may alias out+1.
// ---------------------------------------------------------------------------
__global__ __launch_bounds__(TPB)
void sinkhorn_main(const float* Cm, const float* __restrict__ CT,
                   float* __restrict__ u0, float* __restrict__ u1,
                   float* __restrict__ v,
                   unsigned long long* __restrict__ slots,
                   float* out, int c_aligned, int use_ct)
{
    __shared__ float swave[NWB];
    __shared__ float sred;
    const int t    = threadIdx.x;
    const int lane = t & 63;
    const int w    = t >> 6;
    const int b    = blockIdx.x;
    const int wid0 = b * NWB + w;

    unsigned ep = 0;

    float* ucur  = u0;
    float* unext = u1;
    float* ulast = u1;

    for (int it = 0; it < MAX_IT; ++it) {
        // ---- row pass: u_new[i] = eps*(log_a - lse_j((v_j - C_ij)/eps))
        {
            const int iA = wid0, iB = wid0 + NWAVES;
            float b32[32], cA[32], cB[32];
            load_row32(v, lane, 1, b32);
            load_row32(Cm + (size_t)iA * NN, lane, c_aligned, cA);
            load_row32(Cm + (size_t)iB * NN, lane, c_aligned, cB);
            float lseA = wave_lse(cA, b32);
            float lseB = wave_lse(cB, b32);
            if (lane == 0) {
                float unA = EPS * (LOG_AB - lseA);
                float unB = EPS * (LOG_AB - lseB);
                swave[w] = fabsf(unA - ucur[iA]) + fabsf(unB - ucur[iB]);
                unext[iA] = unA;
                unext[iB] = unB;
            }
        }
        float rowdiff = gbar(slots, ++ep, swave, &sred);

        // ---- col pass: v_new[j] = eps*(log_b - lse_i((u_i - C_ij)/eps))
        {
            const int jA = wid0, jB = wid0 + NWAVES;
            float b32[32];
            load_row32(unext, lane, 1, b32);
            float lseA, lseB;
            if (use_ct) {
                float cA[32], cB[32];
                load_row32(CT + (size_t)jA * NN, lane, 1, cA);
                load_row32(CT + (size_t)jB * NN, lane, 1, cB);
                lseA = wave_lse(cA, b32);
                lseB = wave_lse(cB, b32);
            } else {
                float cA[32], cB[32];   // strided fallback
#pragma unroll
                for (int k = 0; k < 8; ++k)
#pragma unroll
                    for (int kk = 0; kk < 4; ++kk) {
                        size_t i2 = (size_t)(4 * (lane + 64 * k) + kk) * NN;
                        cA[4*k+kk] = Cm[i2 + jA];
                        cB[4*k+kk] = Cm[i2 + jB];
                    }
                lseA = wave_lse(cA, b32);
                lseB = wave_lse(cB, b32);
            }
            if (lane == 0) {
                float vnA = EPS * (LOG_AB - lseA);
                float vnB = EPS * (LOG_AB - lseB);
                swave[w] = fabsf(vnA - v[jA]) + fabsf(vnB - v[jB]);
                v[jA] = vnA;
                v[jB] = vnB;
            }
        }
        float coldiff = gbar(slots, ++ep, swave, &sred);

        ulast = unext;
        if (rowdiff + coldiff < THRESH) break;   // uniform across grid
        float* tmp = ucur; ucur = unext; unext = tmp;
    }

    // ---- epilogue: pi = exp((u_i + v_j - C_ij)/eps), cost = sum(pi*C)
    const float* uf = ulast;
    float cpart = 0.0f;
    {
        float b32[32];
        load_row32(v, lane, 1, b32);
#pragma unroll
        for (int r = 0; r < RPW; ++r) {
            int i = wid0 + r * NWAVES;
            float c32[32];
            load_row32(Cm + (size_t)i * NN, lane, c_aligned, c32);
            float ui = uf[i];
            float* orow = out + 1 + (size_t)i * NN;
#pragma unroll
            for (int k = 0; k < 8; ++k) {
#pragma unroll
                for (int kk = 0; kk < 4; ++kk) {
                    float cc = c32[4*k+kk];
                    float p  = __expf((ui + b32[4*k+kk] - cc) * INV_EPS);
                    cpart = fmaf(p, cc, cpart);
                    orow[4 * (lane + 64 * k) + kk] = p;  // safe even if Cm==out+1
                }
            }
        }
    }
#pragma unroll
    for (int off = 1; off < 64; off <<= 1) cpart += __shfl_xor(cpart, off);
    if (lane == 0) swave[w] = cpart;
    float total = gbar(slots, ++ep, swave, &sred);
    if (b == 0 && t == 0) out[0] = total;
}

// ---------------------------------------------------------------------------
extern "C" void kernel_launch(void* const* d_in, const int* in_sizes, int n_in,
                              void* d_out, int out_size, void* d_ws, size_t ws_size,
                              hipStream_t stream)
{
    (void)in_sizes; (void)n_in; (void)out_size;
    const float* x = (const float*)d_in[0];
    const float* y = (const float*)d_in[1];
    float* out = (float*)d_out;
    char*  ws  = (char*)d_ws;

    const size_t CB = (size_t)NN * NN * sizeof(float);   // 16 MiB
    const size_t ZZ = 64 * 1024;

    float *Cm, *CT, *zz;
    int c_aligned, use_ct;
    if (ws_size >= 2 * CB + ZZ) {             // preferred: C, CT, state in ws
        Cm = (float*)ws; CT = (float*)(ws + CB); zz = (float*)(ws + 2 * CB);
        c_aligned = 1; use_ct = 1;
    } else if (ws_size >= CB + ZZ) {          // C in out+1, CT in ws
        Cm = out + 1; CT = (float*)ws; zz = (float*)(ws + CB);
        c_aligned = 0; use_ct = 1;
    } else {                                  // C in out+1, no CT (strided)
        Cm = out + 1; CT = nullptr; zz = (float*)ws;
        c_aligned = 0; use_ct = 0;
    }
    // layout (floats): u0[0,2048) v[2048,4096) slots[4096,8192) u1[8192,10240)
    float*              u0    = zz;
    float*              v     = zz + 2048;
    unsigned long long* slots = (unsigned long long*)(zz + 4096);  // 16 KiB
    float*              u1    = zz + 8192;

    hipLaunchKernelGGL(build_cost, dim3(32, 32), dim3(TPB_B), 0, stream,
                       x, y, Cm, CT, zz, c_aligned, use_ct);

    const float* Cmc = Cm;
    const float* CTc = CT;
    void* args[] = { (void*)&Cmc, (void*)&CTc, (void*)&u0, (void*)&u1,
                     (void*)&v, (void*)&slots,
                     (void*)&out, (void*)&c_aligned, (void*)&use_ct };
    hipLaunchCooperativeKernel((void*)sinkhorn_main, dim3(NB), dim3(TPB),
                               args, 0, stream);
}

// Round 5
// 1138.050 us; speedup vs baseline: 15.5495x; 1.4063x over previous
//
#include <hip/hip_runtime.h>
#include <cstddef>

static constexpr int   NN      = 2048;
static constexpr int   TPB_B   = 256;   // build_cost block
static constexpr int   TPB     = 512;   // main kernel block (8 waves)
static constexpr int   NWB     = TPB / 64;          // 8 waves/block
static constexpr int   NB      = 256;               // main grid blocks (1/CU)
static constexpr int   SLOTSTR = 16;                // u64 stride: 1 slot / 128B line
static constexpr int   MAX_IT  = 100;
static constexpr float EPS     = 0.1f;
static constexpr float INV_EPS = 10.0f;
// logf(1/2048 + 1e-8)
static constexpr float LOG_AB  = -7.6245985063594f;
static constexpr float THRESH  = 0.1f;

#define ALOAD(p)     __hip_atomic_load((p),  __ATOMIC_RELAXED, __HIP_MEMORY_SCOPE_AGENT)
#define ASTORE(p, x) __hip_atomic_store((p), (x), __ATOMIC_RELAXED, __HIP_MEMORY_SCOPE_AGENT)

// ---------------------------------------------------------------------------
// Cost matrix build + state zeroing. C[i][j] = sum_d (x[i,d]-y[j,d])^2.
// ---------------------------------------------------------------------------
__global__ __launch_bounds__(TPB_B)
void build_cost(const float* __restrict__ x, const float* __restrict__ y,
                float* __restrict__ C, float* __restrict__ CT,
                float* __restrict__ zz, int c_aligned, int use_ct)
{
    __shared__ float xs[64][65];
    __shared__ float ys[64][65];
    const int t  = threadIdx.x;
    const int bi = blockIdx.y, bj = blockIdx.x;

    // block (0,0) zeroes state region: u0|v|u1|flag|slots in [0,16384) floats
    if (bi == 0 && bj == 0)
        for (int idx = t; idx < 16384; idx += TPB_B) zz[idx] = 0.0f;

#pragma unroll
    for (int k = 0; k < 16; ++k) {
        int idx = t + TPB_B * k;
        int r = idx >> 6, c = idx & 63;
        xs[r][c] = x[(size_t)(bi * 64 + r) * 64 + c];
        ys[r][c] = y[(size_t)(bj * 64 + r) * 64 + c];
    }
    __syncthreads();

    const int ti0 = (t >> 4) * 4;
    const int tj0 = (t & 15) * 4;
    float acc[4][4] = {};
#pragma unroll 8
    for (int d = 0; d < 64; ++d) {
        float xv[4], yv[4];
#pragma unroll
        for (int k = 0; k < 4; ++k) xv[k] = xs[ti0 + k][d];
#pragma unroll
        for (int l = 0; l < 4; ++l) yv[l] = ys[tj0 + l][d];
#pragma unroll
        for (int k = 0; k < 4; ++k)
#pragma unroll
            for (int l = 0; l < 4; ++l) {
                float df = xv[k] - yv[l];
                acc[k][l] = fmaf(df, df, acc[k][l]);
            }
    }

#pragma unroll
    for (int k = 0; k < 4; ++k) {
        size_t off = (size_t)(bi * 64 + ti0 + k) * NN + bj * 64 + tj0;
        if (c_aligned) {
            *(float4*)(C + off) = make_float4(acc[k][0], acc[k][1], acc[k][2], acc[k][3]);
        } else {
            C[off + 0] = acc[k][0]; C[off + 1] = acc[k][1];
            C[off + 2] = acc[k][2]; C[off + 3] = acc[k][3];
        }
    }
    if (use_ct) {
#pragma unroll
        for (int l = 0; l < 4; ++l) {
            size_t off = (size_t)(bj * 64 + tj0 + l) * NN + bi * 64 + ti0;
            *(float4*)(CT + off) = make_float4(acc[0][l], acc[1][l], acc[2][l], acc[3][l]);
        }
    }
}

// ---------------------------------------------------------------------------
// Helpers
// ---------------------------------------------------------------------------
__device__ __forceinline__ void load_row32(const float* row, int lane,
                                           int aligned, float c[32])
{
    if (aligned) {
        const float4* r4 = (const float4*)row;
#pragma unroll
        for (int k = 0; k < 8; ++k) {
            float4 A = r4[lane + 64 * k];
            c[4*k+0] = A.x; c[4*k+1] = A.y; c[4*k+2] = A.z; c[4*k+3] = A.w;
        }
    } else {
#pragma unroll
        for (int k = 0; k < 8; ++k) {
            const float* p = row + 4 * (lane + 64 * k);
            c[4*k+0] = p[0]; c[4*k+1] = p[1]; c[4*k+2] = p[2]; c[4*k+3] = p[3];
        }
    }
}

// stage 2048 floats from global (coherent bypass loads) into LDS
__device__ __forceinline__ void stage2048(float* gp, float* sv, int t)
{
#pragma unroll
    for (int k = 0; k < 4; ++k) {
        int idx = t + TPB * k;
        sv[idx] = ALOAD(&gp[idx]);
    }
    __syncthreads();
}

__device__ __forceinline__ void lds_row32(const float* sv, int lane, float b[32])
{
    const float4* s4 = (const float4*)sv;
#pragma unroll
    for (int k = 0; k < 8; ++k) {
        float4 A = s4[lane + 64 * k];
        b[4*k+0] = A.x; b[4*k+1] = A.y; b[4*k+2] = A.z; b[4*k+3] = A.w;
    }
}

// wave-level lse of (b-c)*INV_EPS over 2048 elems (32/lane); result on all lanes
__device__ __forceinline__ float wave_lse(float c[32], const float b[32])
{
#pragma unroll
    for (int k = 0; k < 32; ++k) c[k] = (b[k] - c[k]) * INV_EPS;
    float m = c[0];
#pragma unroll
    for (int k = 1; k < 32; ++k) m = fmaxf(m, c[k]);
    float s = 0.0f;
#pragma unroll
    for (int k = 0; k < 32; ++k) s += __expf(c[k] - m);
#pragma unroll
    for (int off = 1; off < 64; off <<= 1) {
        float m2 = __shfl_xor(m, off);
        float s2 = __shfl_xor(s, off);
        float nm = fmaxf(m, m2);
        s = __expf(m - nm) * s + __expf(m2 - nm) * s2;
        m = nm;
    }
    return m + __logf(s);
}

// ---------------------------------------------------------------------------
// Two-hop fence-free barrier. NO acquire/release fences -> L2/L1 stay warm.
// Ordering: each thread s_waitcnt vmcnt(0) (its coherent u/v stores acked at
// LLC) -> __syncthreads -> t0 writes per-block slot {epoch|pdiff} (own 128B
// line) -> block0 wave0 polls all 256 slots (4/lane), reduces pdiffs, posts
// single release flag {epoch|sum} -> everyone polls the one flag line.
// All shared data crosses via RELAXED+AGENT bypass atomics (always fresh).
// ---------------------------------------------------------------------------
__device__ __forceinline__ float gbar(unsigned long long* slots,
                                      unsigned long long* flagp,
                                      unsigned epoch, const float* swave)
{
    const int t = threadIdx.x;
    asm volatile("s_waitcnt vmcnt(0)" ::: "memory");
    __syncthreads();
    if (t == 0) {
        float p = 0.0f;
#pragma unroll
        for (int w = 0; w < NWB; ++w) p += swave[w];
        unsigned long long val = ((unsigned long long)epoch << 32) |
                                 (unsigned long long)__float_as_uint(p);
        ASTORE(&slots[(size_t)blockIdx.x * SLOTSTR], val);
    }
    if (blockIdx.x == 0 && t < 64) {
        float d;
        for (;;) {
            bool ok = true;
            d = 0.0f;
#pragma unroll
            for (int k = 0; k < 4; ++k) {
                unsigned long long s = ALOAD(&slots[(size_t)(4 * t + k) * SLOTSTR]);
                ok &= ((unsigned)(s >> 32) >= epoch);
                d += __uint_as_float((unsigned)s);
            }
            if (__ballot(ok) == ~0ull) break;
            __builtin_amdgcn_s_sleep(1);
        }
#pragma unroll
        for (int off = 1; off < 64; off <<= 1) d += __shfl_xor(d, off);
        if (t == 0) {
            unsigned long long val = ((unsigned long long)epoch << 32) |
                                     (unsigned long long)__float_as_uint(d);
            ASTORE(flagp, val);
        }
    }
    unsigned long long f;
    for (;;) {
        f = ALOAD(flagp);
        if ((unsigned)(f >> 32) >= epoch) break;
        __builtin_amdgcn_s_sleep(1);
    }
    asm volatile("" ::: "memory");
    return __uint_as_float((unsigned)f);
}

// ---------------------------------------------------------------------------
// Main cooperative kernel. 256 blocks x 512 thr; wave w of block b owns row
// i = b*8 + w (its 16 KB of C rows stay L1/L2-resident: no fences!).
// Cm may alias out+1.
// ---------------------------------------------------------------------------
__global__ __launch_bounds__(TPB)
void sinkhorn_main(const float* Cm, const float* __restrict__ CT,
                   float* __restrict__ u0, float* __restrict__ u1,
                   float* __restrict__ v,
                   unsigned long long* __restrict__ slots,
                   unsigned long long* __restrict__ flagp,
                   float* out, int c_aligned, int use_ct)
{
    __shared__ float sv[2048];
    __shared__ float swave[NWB];
    const int t    = threadIdx.x;
    const int lane = t & 63;
    const int w    = t >> 6;
    const int b    = blockIdx.x;
    const int i    = b * NWB + w;       // this wave's row == col index

    unsigned ep = 0;

    float* ucur  = u0;
    float* unext = u1;
    float* ulast = u1;

    for (int it = 0; it < MAX_IT; ++it) {
        // ---- row pass: u_new[i] = eps*(log_a - lse_j((v_j - C_ij)/eps))
        float rowdiff;
        {
            float uold = 0.0f;
            if (lane == 0) uold = ALOAD(&ucur[i]);   // prefetch, hidden by stage
            stage2048(v, sv, t);
            float b32[32], c32[32];
            lds_row32(sv, lane, b32);
            load_row32(Cm + (size_t)i * NN, lane, c_aligned, c32);
            float lse = wave_lse(c32, b32);
            if (lane == 0) {
                float un = EPS * (LOG_AB - lse);
                ASTORE(&unext[i], un);
                swave[w] = fabsf(un - uold);
            }
            rowdiff = gbar(slots, flagp, ++ep, swave);
        }

        // ---- col pass: v_new[j] = eps*(log_b - lse_i((u_i - C_ij)/eps))
        float coldiff;
        {
            float vold = 0.0f;
            if (lane == 0) vold = ALOAD(&v[i]);
            stage2048(unext, sv, t);
            float b32[32], c32[32];
            lds_row32(sv, lane, b32);
            if (use_ct) {
                load_row32(CT + (size_t)i * NN, lane, 1, c32);
            } else {
#pragma unroll
                for (int k = 0; k < 8; ++k)
#pragma unroll
                    for (int kk = 0; kk < 4; ++kk)
                        c32[4*k+kk] = Cm[(size_t)(4 * (lane + 64 * k) + kk) * NN + i];
            }
            float lse = wave_lse(c32, b32);
            if (lane == 0) {
                float vn = EPS * (LOG_AB - lse);
                ASTORE(&v[i], vn);
                swave[w] = fabsf(vn - vold);
            }
            coldiff = gbar(slots, flagp, ++ep, swave);
        }

        ulast = unext;
        if (rowdiff + coldiff < THRESH) break;   // uniform across grid
        float* tmp = ucur; ucur = unext; unext = tmp;
    }

    // ---- epilogue: pi = exp((u_i + v_j - C_ij)/eps), cost = sum(pi*C)
    float cpart = 0.0f;
    {
        float ui_s = 0.0f;
        if (lane == 0) ui_s = ALOAD(&ulast[i]);
        stage2048(v, sv, t);
        float ui = __shfl(ui_s, 0);
        float b32[32], c32[32];
        lds_row32(sv, lane, b32);
        load_row32(Cm + (size_t)i * NN, lane, c_aligned, c32);
        float* orow = out + 1 + (size_t)i * NN;
#pragma unroll
        for (int k = 0; k < 8; ++k) {
#pragma unroll
            for (int kk = 0; kk < 4; ++kk) {
                float cc = c32[4*k+kk];
                float p  = __expf((ui + b32[4*k+kk] - cc) * INV_EPS);
                cpart = fmaf(p, cc, cpart);
                orow[4 * (lane + 64 * k) + kk] = p;  // safe even if Cm==out+1
            }
        }
    }
#pragma unroll
    for (int off = 1; off < 64; off <<= 1) cpart += __shfl_xor(cpart, off);
    if (lane == 0) swave[w] = cpart;
    float total = gbar(slots, flagp, ++ep, swave);
    if (b == 0 && t == 0) out[0] = total;
}

// ---------------------------------------------------------------------------
extern "C" void kernel_launch(void* const* d_in, const int* in_sizes, int n_in,
                              void* d_out, int out_size, void* d_ws, size_t ws_size,
                              hipStream_t stream)
{
    (void)in_sizes; (void)n_in; (void)out_size;
    const float* x = (const float*)d_in[0];
    const float* y = (const float*)d_in[1];
    float* out = (float*)d_out;
    char*  ws  = (char*)d_ws;

    const size_t CB = (size_t)NN * NN * sizeof(float);   // 16 MiB
    const size_t ZZ = 128 * 1024;

    float *Cm, *CT, *zz;
    int c_aligned, use_ct;
    if (ws_size >= 2 * CB + ZZ) {             // preferred: C, CT, state in ws
        Cm = (float*)ws; CT = (float*)(ws + CB); zz = (float*)(ws + 2 * CB);
        c_aligned = 1; use_ct = 1;
    } else if (ws_size >= CB + ZZ) {          // C in out+1, CT in ws
        Cm = out + 1; CT = (float*)ws; zz = (float*)(ws + CB);
        c_aligned = 0; use_ct = 1;
    } else {                                  // C in out+1, no CT (strided)
        Cm = out + 1; CT = nullptr; zz = (float*)ws;
        c_aligned = 0; use_ct = 0;
    }
    // layout (floats): u0[0,2048) v[2048,4096) u1[4096,6144)
    //                  flag @6272 (own line)   slots[8192,16384) (256x128B)
    float*              u0    = zz;
    float*              v     = zz + 2048;
    float*              u1    = zz + 4096;
    unsigned long long* flagp = (unsigned long long*)(zz + 6272);
    unsigned long long* slots = (unsigned long long*)(zz + 8192);

    hipLaunchKernelGGL(build_cost, dim3(32, 32), dim3(TPB_B), 0, stream,
                       x, y, Cm, CT, zz, c_aligned, use_ct);

    const float* Cmc = Cm;
    const float* CTc = CT;
    void* args[] = { (void*)&Cmc, (void*)&CTc, (void*)&u0, (void*)&u1,
                     (void*)&v, (void*)&slots, (void*)&flagp,
                     (void*)&out, (void*)&c_aligned, (void*)&use_ct };
    hipLaunchCooperativeKernel((void*)sinkhorn_main, dim3(NB), dim3(TPB),
                               args, 0, stream);
}